// Round 5
// baseline (234.554 us; speedup 1.0000x reference)
//
#include <hip/hip_runtime.h>

#define NROWS 524288
#define DDIM  64
#define HCENT 256
#define GRID  512
#define CPB   4   // 256-row chunks per block: 512*4*256 = 524288

typedef short bf16x8 __attribute__((ext_vector_type(8)));
typedef float f32x4  __attribute__((ext_vector_type(4)));

#define LOG2E 1.4426950408889634f
#define K2L   2.8853900817779268f   // 2*log2(e)
#define BIASF 80.0f

__device__ __forceinline__ float fast_exp2(float x) {
#if __has_builtin(__builtin_amdgcn_exp2f)
  return __builtin_amdgcn_exp2f(x);
#else
  return exp2f(x);
#endif
}

// nontemporal 16B load/store must go through a NATIVE vector type
// (ext_vector_type), not HIP's struct float4.
__device__ __forceinline__ f32x4 nt_load4(const float* p) {
  return __builtin_nontemporal_load(reinterpret_cast<const f32x4*>(p));
}
__device__ __forceinline__ void nt_store4(float* p, f32x4 v) {
  __builtin_nontemporal_store(v, reinterpret_cast<f32x4*>(p));
}

// Precompute per-center constants into workspace, interleaved:
// cw[2h]   = -(c2[h]*log2e + BIAS)
// cw[2h+1] = w[h]
__global__ __launch_bounds__(256) void rbf_setup(const float* __restrict__ centers,
                                                 const float* __restrict__ w,
                                                 float* __restrict__ cw) {
  int h = threadIdx.x;
  const float* cp = centers + h * DDIM;
  float s = 0.f;
#pragma unroll
  for (int d = 0; d < DDIM; ++d) s = fmaf(cp[d], cp[d], s);
  cw[2 * h]     = -fmaf(s, LOG2E, BIASF);
  cw[2 * h + 1] = w[h];
}

__global__ __launch_bounds__(512, 4) void rbf_main(const float* __restrict__ X,
                                                   const float* __restrict__ bptr,
                                                   const float* __restrict__ centers,
                                                   const float* __restrict__ cw,
                                                   float* __restrict__ out) {
  // Centers as split-bf16 MFMA B-fragments, fragment-ordered for conflict-free
  // ds_read_b128: index = (ct*2+kc)*64 + lane, 16B per lane. 32KB+32KB+2KB=66KB
  // -> 2 blocks/CU (block=512 => 16 waves/CU, 4 waves/EU).
  __shared__ int4 BH[16 * 2 * 64];
  __shared__ int4 BL[16 * 2 * 64];
  __shared__ float2 CWs[HCENT];   // (mc, w) per center

  const int tid  = threadIdx.x;
  const int wave = tid >> 6;      // 0..7
  const int lane = tid & 63;
  const int q    = lane >> 4;     // k-group / row-quad
  const int c    = lane & 15;     // col within tile (and A-row at load)

  // ---- stage centers (once per block; 8 waves x 4 (ct,kc) pairs) ----
#pragma unroll
  for (int i = 0; i < 4; ++i) {
    int pair = wave * 4 + i;      // 0..31
    int ct = pair >> 1;
    int kc = pair & 1;
    const float* src = centers + (ct * 16 + c) * DDIM + kc * 32 + q * 8;
    float4 f0 = reinterpret_cast<const float4*>(src)[0];
    float4 f1 = reinterpret_cast<const float4*>(src)[1];
    float xs[8] = {f0.x, f0.y, f0.z, f0.w, f1.x, f1.y, f1.z, f1.w};
    int hp[4], lp[4];
#pragma unroll
    for (int p = 0; p < 4; ++p) {
      unsigned u0 = __float_as_uint(xs[2 * p]);
      unsigned u1 = __float_as_uint(xs[2 * p + 1]);
      float l0 = xs[2 * p]     - __uint_as_float(u0 & 0xFFFF0000u);
      float l1 = xs[2 * p + 1] - __uint_as_float(u1 & 0xFFFF0000u);
      hp[p] = (int)((u1 & 0xFFFF0000u) | (u0 >> 16));
      lp[p] = (int)((__float_as_uint(l1) & 0xFFFF0000u) | (__float_as_uint(l0) >> 16));
    }
    int idx = pair * 64 + lane;
    BH[idx] = make_int4(hp[0], hp[1], hp[2], hp[3]);
    BL[idx] = make_int4(lp[0], lp[1], lp[2], lp[3]);
  }
  // stage cw: 512 threads -> 512 floats
  reinterpret_cast<float*>(CWs)[tid] = cw[tid];

  float bval = bptr[0];

  __syncthreads();  // LDS read-only hereafter; no barrier in the sweep loop

  const bf16x8* BHv = reinterpret_cast<const bf16x8*>(BH);
  const bf16x8* BLv = reinterpret_cast<const bf16x8*>(BL);

  // ---- software pipeline: raw X for iteration s lives in regs across the
  // previous iteration's sweep (removes the ~900-cyc HBM bubble per s-iter) ----
  f32x4 raw[2][4];

  {
    int rowbase0 = (blockIdx.x * CPB + 0) * 256 + wave * 32;
#pragma unroll
    for (int rt = 0; rt < 2; ++rt) {
      const float* rp = X + (rowbase0 + rt * 16 + c) * DDIM + q * 8;
      raw[rt][0] = nt_load4(rp);
      raw[rt][1] = nt_load4(rp + 4);
      raw[rt][2] = nt_load4(rp + 32);
      raw[rt][3] = nt_load4(rp + 36);
    }
  }

#pragma unroll 1
  for (int s = 0; s < CPB; ++s) {
    int rowbase = (blockIdx.x * CPB + s) * 256 + wave * 32;

    // ---- convert raw -> bf16 hi/lo A-fragments + partial x2 (data already here) ----
    bf16x8 ah[2][2], al[2][2];
    float x2p[2];
#pragma unroll
    for (int rt = 0; rt < 2; ++rt) {
      float part = 0.f;
#pragma unroll
      for (int kc = 0; kc < 2; ++kc) {
        f32x4 f0 = raw[rt][kc * 2];
        f32x4 f1 = raw[rt][kc * 2 + 1];
        float xs[8] = {f0.x, f0.y, f0.z, f0.w, f1.x, f1.y, f1.z, f1.w};
        union { int i[4]; bf16x8 v; } uh, ul;
#pragma unroll
        for (int p = 0; p < 4; ++p) {
          float x0 = xs[2 * p], x1 = xs[2 * p + 1];
          part = fmaf(x0, x0, part);
          part = fmaf(x1, x1, part);
          unsigned u0 = __float_as_uint(x0);
          unsigned u1 = __float_as_uint(x1);
          float l0 = x0 - __uint_as_float(u0 & 0xFFFF0000u);
          float l1 = x1 - __uint_as_float(u1 & 0xFFFF0000u);
          uh.i[p] = (int)((u1 & 0xFFFF0000u) | (u0 >> 16));
          ul.i[p] = (int)((__float_as_uint(l1) & 0xFFFF0000u) | (__float_as_uint(l0) >> 16));
        }
        ah[rt][kc] = uh.v;
        al[rt][kc] = ul.v;
      }
      x2p[rt] = part;   // k-partial; cross-k shfl deferred to epilogue
    }

    // ---- fire-and-forget loads for s+1; they land during the sweep ----
    if (s + 1 < CPB) {
      int rbn = (blockIdx.x * CPB + s + 1) * 256 + wave * 32;
#pragma unroll
      for (int rt = 0; rt < 2; ++rt) {
        const float* rp = X + (rbn + rt * 16 + c) * DDIM + q * 8;
        raw[rt][0] = nt_load4(rp);
        raw[rt][1] = nt_load4(rp + 4);
        raw[rt][2] = nt_load4(rp + 32);
        raw[rt][3] = nt_load4(rp + 36);
      }
    }

    // ---- sweep 16 col-tiles ----
    float psum[2][4] = {{0.f, 0.f, 0.f, 0.f}, {0.f, 0.f, 0.f, 0.f}};
#pragma unroll 2
    for (int ct = 0; ct < 16; ++ct) {
      int idx = ct * 128 + lane;
      bf16x8 bh0 = BHv[idx], bh1 = BHv[idx + 64];
      bf16x8 bl0 = BLv[idx], bl1 = BLv[idx + 64];
      float2 mw = CWs[ct * 16 + c];   // (mc, w) via ds_read_b64, broadcast over q
#pragma unroll
      for (int rt = 0; rt < 2; ++rt) {
        f32x4 acc = {0.f, 0.f, 0.f, 0.f};
        acc = __builtin_amdgcn_mfma_f32_16x16x32_bf16(ah[rt][0], bh0, acc, 0, 0, 0);
        acc = __builtin_amdgcn_mfma_f32_16x16x32_bf16(ah[rt][1], bh1, acc, 0, 0, 0);
        acc = __builtin_amdgcn_mfma_f32_16x16x32_bf16(al[rt][0], bh0, acc, 0, 0, 0);
        acc = __builtin_amdgcn_mfma_f32_16x16x32_bf16(al[rt][1], bh1, acc, 0, 0, 0);
        acc = __builtin_amdgcn_mfma_f32_16x16x32_bf16(ah[rt][0], bl0, acc, 0, 0, 0);
        acc = __builtin_amdgcn_mfma_f32_16x16x32_bf16(ah[rt][1], bl1, acc, 0, 0, 0);
        // contribution = exp2(2L*a - (L*c2+B)) * w; row factor applied later
#pragma unroll
        for (int r = 0; r < 4; ++r) {
          float e = fast_exp2(fmaf(acc[r], K2L, mw.x));
          psum[rt][r] = fmaf(e, mw.y, psum[rt][r]);
        }
      }
    }

    // ---- reduce over the 16 col-lanes, apply row factor, store ----
#pragma unroll
    for (int rt = 0; rt < 2; ++rt) {
      // complete x2 across k-groups now (off the sweep's critical path)
      float part = x2p[rt];
      part += __shfl_xor(part, 16, 64);
      part += __shfl_xor(part, 32, 64);
#pragma unroll
      for (int r = 0; r < 4; ++r) {
        float v = psum[rt][r];
        v += __shfl_xor(v, 1, 64);
        v += __shfl_xor(v, 2, 64);
        v += __shfl_xor(v, 4, 64);
        v += __shfl_xor(v, 8, 64);
        // x2 of row q*4+r lives in lanes with c == q*4+r (replicated over q)
        float x2row = __shfl(part, q * 4 + r, 64);
        float rowf = fast_exp2(fmaf(-LOG2E, x2row, BIASF));
        psum[rt][r] = fmaf(v, rowf, bval);
      }
      if (c == 0) {
        f32x4 o = {psum[rt][0], psum[rt][1], psum[rt][2], psum[rt][3]};
        nt_store4(out + rowbase + rt * 16 + q * 4, o);
      }
    }
  }
}

extern "C" void kernel_launch(void* const* d_in, const int* in_sizes, int n_in,
                              void* d_out, int out_size, void* d_ws, size_t ws_size,
                              hipStream_t stream) {
  const float* X       = (const float*)d_in[0];
  const float* centers = (const float*)d_in[1];
  const float* w       = (const float*)d_in[2];
  const float* b       = (const float*)d_in[3];
  float* out = (float*)d_out;
  float* cw  = (float*)d_ws;   // 512 floats, interleaved (mc, w)

  rbf_setup<<<1, 256, 0, stream>>>(centers, w, cw);
  rbf_main<<<GRID, 512, 0, stream>>>(X, b, centers, cw, out);
}

// Round 6
// 228.452 us; speedup vs baseline: 1.0267x; 1.0267x over previous
//
#include <hip/hip_runtime.h>

#define NROWS 524288
#define DDIM  64
#define HCENT 256
#define GRID  512
#define CPB   4   // 256-row chunks per block: 512*4*256 = 524288

typedef short bf16x8 __attribute__((ext_vector_type(8)));
typedef float f32x4  __attribute__((ext_vector_type(4)));

#define LOG2E 1.4426950408889634f
#define K2L   2.8853900817779268f   // 2*log2(e)
#define BIASF 80.0f

__device__ __forceinline__ float fast_exp2(float x) {
#if __has_builtin(__builtin_amdgcn_exp2f)
  return __builtin_amdgcn_exp2f(x);
#else
  return exp2f(x);
#endif
}

__global__ __launch_bounds__(512, 4) void rbf_main(const float* __restrict__ X,
                                                   const float* __restrict__ bptr,
                                                   const float* __restrict__ centers,
                                                   const float* __restrict__ w,
                                                   float* __restrict__ out) {
  // Centers as split-bf16 MFMA B-fragments, fragment-ordered for conflict-free
  // ds_read_b128: index = (ct*2+kc)*64 + lane, 16B per lane. 32KB+32KB+2KB=66KB
  // -> 2 blocks/CU (block=512 => 16 waves/CU, 4 waves/EU).
  // NOTE: no nontemporal hints anywhere — X (134MB) fits in the 256MB L3
  // across graph replays; nt loads forced full HBM refetch (round-5 regression).
  __shared__ int4 BH[16 * 2 * 64];
  __shared__ int4 BL[16 * 2 * 64];
  __shared__ float2 CWs[HCENT];   // (mc, w) per center, computed in-block

  const int tid  = threadIdx.x;
  const int wave = tid >> 6;      // 0..7
  const int lane = tid & 63;
  const int q    = lane >> 4;     // k-group / row-quad
  const int c    = lane & 15;     // col within tile (and A-row at load)

  // ---- stage centers + compute per-center constants (once per block) ----
  // wave handles cts {wave*2, wave*2+1}, both kc halves of each.
  float c2a[2] = {0.f, 0.f};
#pragma unroll
  for (int i = 0; i < 4; ++i) {
    int pair = wave * 4 + i;      // 0..31
    int ct = pair >> 1;
    int kc = pair & 1;
    const float* src = centers + (ct * 16 + c) * DDIM + kc * 32 + q * 8;
    float4 f0 = reinterpret_cast<const float4*>(src)[0];
    float4 f1 = reinterpret_cast<const float4*>(src)[1];
    float xs[8] = {f0.x, f0.y, f0.z, f0.w, f1.x, f1.y, f1.z, f1.w};
    float ss = 0.f;
    int hp[4], lp[4];
#pragma unroll
    for (int p = 0; p < 4; ++p) {
      float x0 = xs[2 * p], x1 = xs[2 * p + 1];
      ss = fmaf(x0, x0, ss);
      ss = fmaf(x1, x1, ss);
      unsigned u0 = __float_as_uint(x0);
      unsigned u1 = __float_as_uint(x1);
      float l0 = x0 - __uint_as_float(u0 & 0xFFFF0000u);
      float l1 = x1 - __uint_as_float(u1 & 0xFFFF0000u);
      hp[p] = (int)((u1 & 0xFFFF0000u) | (u0 >> 16));
      lp[p] = (int)((__float_as_uint(l1) & 0xFFFF0000u) | (__float_as_uint(l0) >> 16));
    }
    c2a[i >> 1] += ss;
    int idx = pair * 64 + lane;
    BH[idx] = make_int4(hp[0], hp[1], hp[2], hp[3]);
    BL[idx] = make_int4(lp[0], lp[1], lp[2], lp[3]);
  }
  // finish c2 across the 4 q-groups; write (mc, w) for this wave's 32 centers
#pragma unroll
  for (int t = 0; t < 2; ++t) {
    int ct = wave * 2 + t;
    float s2 = c2a[t];
    s2 += __shfl_xor(s2, 16, 64);
    s2 += __shfl_xor(s2, 32, 64);
    if (q == 0) {
      int h = ct * 16 + c;
      CWs[h] = make_float2(-fmaf(s2, LOG2E, BIASF), w[h]);
    }
  }

  float bval = bptr[0];

  __syncthreads();  // LDS read-only hereafter; no barrier in the sweep loop

  const bf16x8* BHv = reinterpret_cast<const bf16x8*>(BH);
  const bf16x8* BLv = reinterpret_cast<const bf16x8*>(BL);

  // ---- software pipeline: raw X for iteration s lives in regs across the
  // previous iteration's sweep (hides the global-load latency per s-iter) ----
  f32x4 raw[2][4];

  {
    int rowbase0 = (blockIdx.x * CPB + 0) * 256 + wave * 32;
#pragma unroll
    for (int rt = 0; rt < 2; ++rt) {
      const float* rp = X + (rowbase0 + rt * 16 + c) * DDIM + q * 8;
      raw[rt][0] = reinterpret_cast<const f32x4*>(rp)[0];
      raw[rt][1] = reinterpret_cast<const f32x4*>(rp)[1];
      raw[rt][2] = reinterpret_cast<const f32x4*>(rp + 32)[0];
      raw[rt][3] = reinterpret_cast<const f32x4*>(rp + 32)[1];
    }
  }

#pragma unroll 1
  for (int s = 0; s < CPB; ++s) {
    int rowbase = (blockIdx.x * CPB + s) * 256 + wave * 32;

    // ---- convert raw -> bf16 hi/lo A-fragments + partial x2 (data already here) ----
    bf16x8 ah[2][2], al[2][2];
    float x2p[2];
#pragma unroll
    for (int rt = 0; rt < 2; ++rt) {
      float part = 0.f;
#pragma unroll
      for (int kc = 0; kc < 2; ++kc) {
        f32x4 f0 = raw[rt][kc * 2];
        f32x4 f1 = raw[rt][kc * 2 + 1];
        float xs[8] = {f0.x, f0.y, f0.z, f0.w, f1.x, f1.y, f1.z, f1.w};
        union { int i[4]; bf16x8 v; } uh, ul;
#pragma unroll
        for (int p = 0; p < 4; ++p) {
          float x0 = xs[2 * p], x1 = xs[2 * p + 1];
          part = fmaf(x0, x0, part);
          part = fmaf(x1, x1, part);
          unsigned u0 = __float_as_uint(x0);
          unsigned u1 = __float_as_uint(x1);
          float l0 = x0 - __uint_as_float(u0 & 0xFFFF0000u);
          float l1 = x1 - __uint_as_float(u1 & 0xFFFF0000u);
          uh.i[p] = (int)((u1 & 0xFFFF0000u) | (u0 >> 16));
          ul.i[p] = (int)((__float_as_uint(l1) & 0xFFFF0000u) | (__float_as_uint(l0) >> 16));
        }
        ah[rt][kc] = uh.v;
        al[rt][kc] = ul.v;
      }
      x2p[rt] = part;   // k-partial; cross-k shfl deferred to epilogue
    }

    // ---- fire-and-forget loads for s+1; they land during the sweep ----
    if (s + 1 < CPB) {
      int rbn = (blockIdx.x * CPB + s + 1) * 256 + wave * 32;
#pragma unroll
      for (int rt = 0; rt < 2; ++rt) {
        const float* rp = X + (rbn + rt * 16 + c) * DDIM + q * 8;
        raw[rt][0] = reinterpret_cast<const f32x4*>(rp)[0];
        raw[rt][1] = reinterpret_cast<const f32x4*>(rp)[1];
        raw[rt][2] = reinterpret_cast<const f32x4*>(rp + 32)[0];
        raw[rt][3] = reinterpret_cast<const f32x4*>(rp + 32)[1];
      }
    }

    // ---- sweep 16 col-tiles ----
    float psum[2][4] = {{0.f, 0.f, 0.f, 0.f}, {0.f, 0.f, 0.f, 0.f}};
#pragma unroll 2
    for (int ct = 0; ct < 16; ++ct) {
      int idx = ct * 128 + lane;
      bf16x8 bh0 = BHv[idx], bh1 = BHv[idx + 64];
      bf16x8 bl0 = BLv[idx], bl1 = BLv[idx + 64];
      float2 mw = CWs[ct * 16 + c];   // (mc, w) via ds_read_b64, broadcast over q
#pragma unroll
      for (int rt = 0; rt < 2; ++rt) {
        f32x4 acc = {0.f, 0.f, 0.f, 0.f};
        acc = __builtin_amdgcn_mfma_f32_16x16x32_bf16(ah[rt][0], bh0, acc, 0, 0, 0);
        acc = __builtin_amdgcn_mfma_f32_16x16x32_bf16(ah[rt][1], bh1, acc, 0, 0, 0);
        acc = __builtin_amdgcn_mfma_f32_16x16x32_bf16(al[rt][0], bh0, acc, 0, 0, 0);
        acc = __builtin_amdgcn_mfma_f32_16x16x32_bf16(al[rt][1], bh1, acc, 0, 0, 0);
        acc = __builtin_amdgcn_mfma_f32_16x16x32_bf16(ah[rt][0], bl0, acc, 0, 0, 0);
        acc = __builtin_amdgcn_mfma_f32_16x16x32_bf16(ah[rt][1], bl1, acc, 0, 0, 0);
        // contribution = exp2(2L*a - (L*c2+B)) * w; row factor applied later
#pragma unroll
        for (int r = 0; r < 4; ++r) {
          float e = fast_exp2(fmaf(acc[r], K2L, mw.x));
          psum[rt][r] = fmaf(e, mw.y, psum[rt][r]);
        }
      }
    }

    // ---- reduce over the 16 col-lanes, apply row factor, store ----
#pragma unroll
    for (int rt = 0; rt < 2; ++rt) {
      // complete x2 across k-groups now (off the sweep's critical path)
      float part = x2p[rt];
      part += __shfl_xor(part, 16, 64);
      part += __shfl_xor(part, 32, 64);
#pragma unroll
      for (int r = 0; r < 4; ++r) {
        float v = psum[rt][r];
        v += __shfl_xor(v, 1, 64);
        v += __shfl_xor(v, 2, 64);
        v += __shfl_xor(v, 4, 64);
        v += __shfl_xor(v, 8, 64);
        // x2 of row q*4+r lives in lanes with c == q*4+r (replicated over q)
        float x2row = __shfl(part, q * 4 + r, 64);
        float rowf = fast_exp2(fmaf(-LOG2E, x2row, BIASF));
        psum[rt][r] = fmaf(v, rowf, bval);
      }
      if (c == 0) {
        f32x4 o = {psum[rt][0], psum[rt][1], psum[rt][2], psum[rt][3]};
        *reinterpret_cast<f32x4*>(out + rowbase + rt * 16 + q * 4) = o;
      }
    }
  }
}

extern "C" void kernel_launch(void* const* d_in, const int* in_sizes, int n_in,
                              void* d_out, int out_size, void* d_ws, size_t ws_size,
                              hipStream_t stream) {
  const float* X       = (const float*)d_in[0];
  const float* centers = (const float*)d_in[1];
  const float* w       = (const float*)d_in[2];
  const float* b       = (const float*)d_in[3];
  float* out = (float*)d_out;

  rbf_main<<<GRID, 512, 0, stream>>>(X, b, centers, w, out);
}

// Round 7
// 225.731 us; speedup vs baseline: 1.0391x; 1.0121x over previous
//
#include <hip/hip_runtime.h>

#define NROWS 524288
#define DDIM  64
#define HCENT 256
#define GRID  512
#define CPB   4   // 256-row chunks per block: 512*4*256 = 524288

typedef short bf16x8 __attribute__((ext_vector_type(8)));
typedef float f32x4  __attribute__((ext_vector_type(4)));

#define LOG2E 1.4426950408889634f
#define K2L   2.8853900817779268f   // 2*log2(e)
#define BIASF 80.0f

__device__ __forceinline__ float fast_exp2(float x) {
#if __has_builtin(__builtin_amdgcn_exp2f)
  return __builtin_amdgcn_exp2f(x);
#else
  return exp2f(x);
#endif
}

// waves_per_eu pinned to (4,4): round-6 showed __launch_bounds__(512,4) lets
// the allocator chase 8 waves/EU -> 64 VGPRs -> 56 MB of scratch spill.
// LDS (66 KB) caps residency at 2 blocks/CU = 16 waves/CU anyway, so a
// 128-VGPR budget costs zero occupancy.
__global__ __attribute__((amdgpu_flat_work_group_size(512, 512),
                          amdgpu_waves_per_eu(4, 4)))
void rbf_main(const float* __restrict__ X,
              const float* __restrict__ bptr,
              const float* __restrict__ centers,
              const float* __restrict__ w,
              float* __restrict__ out) {
  // Centers as split-bf16 MFMA B-fragments, fragment-ordered for conflict-free
  // ds_read_b128: index = (ct*2+kc)*64 + lane, 16B per lane. 32KB+32KB+2KB=66KB.
  // No nontemporal hints: X (134MB) fits the 256MB L3 across graph replays.
  __shared__ int4 BH[16 * 2 * 64];
  __shared__ int4 BL[16 * 2 * 64];
  __shared__ float2 CWs[HCENT];   // (mc, w) per center, computed in-block

  const int tid  = threadIdx.x;
  const int wave = tid >> 6;      // 0..7
  const int lane = tid & 63;
  const int q    = lane >> 4;     // k-group / row-quad
  const int c    = lane & 15;     // col within tile (and A-row at load)

  // ---- stage centers + compute per-center constants (once per block) ----
  float c2a[2] = {0.f, 0.f};
#pragma unroll
  for (int i = 0; i < 4; ++i) {
    int pair = wave * 4 + i;      // 0..31
    int ct = pair >> 1;
    int kc = pair & 1;
    const float* src = centers + (ct * 16 + c) * DDIM + kc * 32 + q * 8;
    float4 f0 = reinterpret_cast<const float4*>(src)[0];
    float4 f1 = reinterpret_cast<const float4*>(src)[1];
    float xs[8] = {f0.x, f0.y, f0.z, f0.w, f1.x, f1.y, f1.z, f1.w};
    float ss = 0.f;
    int hp[4], lp[4];
#pragma unroll
    for (int p = 0; p < 4; ++p) {
      float x0 = xs[2 * p], x1 = xs[2 * p + 1];
      ss = fmaf(x0, x0, ss);
      ss = fmaf(x1, x1, ss);
      unsigned u0 = __float_as_uint(x0);
      unsigned u1 = __float_as_uint(x1);
      float l0 = x0 - __uint_as_float(u0 & 0xFFFF0000u);
      float l1 = x1 - __uint_as_float(u1 & 0xFFFF0000u);
      hp[p] = (int)((u1 & 0xFFFF0000u) | (u0 >> 16));
      lp[p] = (int)((__float_as_uint(l1) & 0xFFFF0000u) | (__float_as_uint(l0) >> 16));
    }
    c2a[i >> 1] += ss;
    int idx = pair * 64 + lane;
    BH[idx] = make_int4(hp[0], hp[1], hp[2], hp[3]);
    BL[idx] = make_int4(lp[0], lp[1], lp[2], lp[3]);
  }
  // finish c2 across the 4 q-groups; write (mc, w) for this wave's 32 centers
#pragma unroll
  for (int t = 0; t < 2; ++t) {
    int ct = wave * 2 + t;
    float s2 = c2a[t];
    s2 += __shfl_xor(s2, 16, 64);
    s2 += __shfl_xor(s2, 32, 64);
    if (q == 0) {
      int h = ct * 16 + c;
      CWs[h] = make_float2(-fmaf(s2, LOG2E, BIASF), w[h]);
    }
  }

  float bval = bptr[0];

  __syncthreads();  // LDS read-only hereafter; no barrier in the sweep loop

  const bf16x8* BHv = reinterpret_cast<const bf16x8*>(BH);
  const bf16x8* BLv = reinterpret_cast<const bf16x8*>(BL);

  // ---- software pipeline: raw X for iteration s lives in regs across the
  // previous iteration's sweep (hides the global-load latency per s-iter) ----
  f32x4 raw[2][4];

  {
    int rowbase0 = (blockIdx.x * CPB + 0) * 256 + wave * 32;
#pragma unroll
    for (int rt = 0; rt < 2; ++rt) {
      const float* rp = X + (rowbase0 + rt * 16 + c) * DDIM + q * 8;
      raw[rt][0] = reinterpret_cast<const f32x4*>(rp)[0];
      raw[rt][1] = reinterpret_cast<const f32x4*>(rp)[1];
      raw[rt][2] = reinterpret_cast<const f32x4*>(rp + 32)[0];
      raw[rt][3] = reinterpret_cast<const f32x4*>(rp + 32)[1];
    }
  }

#pragma unroll 1
  for (int s = 0; s < CPB; ++s) {
    int rowbase = (blockIdx.x * CPB + s) * 256 + wave * 32;

    // ---- convert raw -> bf16 hi/lo A-fragments + partial x2 ----
    bf16x8 ah[2][2], al[2][2];
    float x2p[2];
#pragma unroll
    for (int rt = 0; rt < 2; ++rt) {
      float part = 0.f;
#pragma unroll
      for (int kc = 0; kc < 2; ++kc) {
        f32x4 f0 = raw[rt][kc * 2];
        f32x4 f1 = raw[rt][kc * 2 + 1];
        float xs[8] = {f0.x, f0.y, f0.z, f0.w, f1.x, f1.y, f1.z, f1.w};
        union { int i[4]; bf16x8 v; } uh, ul;
#pragma unroll
        for (int p = 0; p < 4; ++p) {
          float x0 = xs[2 * p], x1 = xs[2 * p + 1];
          part = fmaf(x0, x0, part);
          part = fmaf(x1, x1, part);
          unsigned u0 = __float_as_uint(x0);
          unsigned u1 = __float_as_uint(x1);
          float l0 = x0 - __uint_as_float(u0 & 0xFFFF0000u);
          float l1 = x1 - __uint_as_float(u1 & 0xFFFF0000u);
          uh.i[p] = (int)((u1 & 0xFFFF0000u) | (u0 >> 16));
          ul.i[p] = (int)((__float_as_uint(l1) & 0xFFFF0000u) | (__float_as_uint(l0) >> 16));
        }
        ah[rt][kc] = uh.v;
        al[rt][kc] = ul.v;
      }
      x2p[rt] = part;   // k-partial; cross-k shfl deferred to epilogue
    }

    // ---- fire-and-forget loads for s+1; they land during the sweep ----
    if (s + 1 < CPB) {
      int rbn = (blockIdx.x * CPB + s + 1) * 256 + wave * 32;
#pragma unroll
      for (int rt = 0; rt < 2; ++rt) {
        const float* rp = X + (rbn + rt * 16 + c) * DDIM + q * 8;
        raw[rt][0] = reinterpret_cast<const f32x4*>(rp)[0];
        raw[rt][1] = reinterpret_cast<const f32x4*>(rp)[1];
        raw[rt][2] = reinterpret_cast<const f32x4*>(rp + 32)[0];
        raw[rt][3] = reinterpret_cast<const f32x4*>(rp + 32)[1];
      }
    }

    // ---- sweep 16 col-tiles ----
    float psum[2][4] = {{0.f, 0.f, 0.f, 0.f}, {0.f, 0.f, 0.f, 0.f}};
#pragma unroll 2
    for (int ct = 0; ct < 16; ++ct) {
      int idx = ct * 128 + lane;
      bf16x8 bh0 = BHv[idx], bh1 = BHv[idx + 64];
      bf16x8 bl0 = BLv[idx], bl1 = BLv[idx + 64];
      float2 mw = CWs[ct * 16 + c];   // (mc, w) via ds_read_b64, broadcast over q
#pragma unroll
      for (int rt = 0; rt < 2; ++rt) {
        f32x4 acc = {0.f, 0.f, 0.f, 0.f};
        acc = __builtin_amdgcn_mfma_f32_16x16x32_bf16(ah[rt][0], bh0, acc, 0, 0, 0);
        acc = __builtin_amdgcn_mfma_f32_16x16x32_bf16(ah[rt][1], bh1, acc, 0, 0, 0);
        acc = __builtin_amdgcn_mfma_f32_16x16x32_bf16(al[rt][0], bh0, acc, 0, 0, 0);
        acc = __builtin_amdgcn_mfma_f32_16x16x32_bf16(al[rt][1], bh1, acc, 0, 0, 0);
        acc = __builtin_amdgcn_mfma_f32_16x16x32_bf16(ah[rt][0], bl0, acc, 0, 0, 0);
        acc = __builtin_amdgcn_mfma_f32_16x16x32_bf16(ah[rt][1], bl1, acc, 0, 0, 0);
        // contribution = exp2(2L*a - (L*c2+B)) * w; row factor applied later
#pragma unroll
        for (int r = 0; r < 4; ++r) {
          float e = fast_exp2(fmaf(acc[r], K2L, mw.x));
          psum[rt][r] = fmaf(e, mw.y, psum[rt][r]);
        }
      }
    }

    // ---- reduce over the 16 col-lanes, apply row factor, store ----
#pragma unroll
    for (int rt = 0; rt < 2; ++rt) {
      // complete x2 across k-groups now (off the sweep's critical path)
      float part = x2p[rt];
      part += __shfl_xor(part, 16, 64);
      part += __shfl_xor(part, 32, 64);
#pragma unroll
      for (int r = 0; r < 4; ++r) {
        float v = psum[rt][r];
        v += __shfl_xor(v, 1, 64);
        v += __shfl_xor(v, 2, 64);
        v += __shfl_xor(v, 4, 64);
        v += __shfl_xor(v, 8, 64);
        // x2 of row q*4+r lives in lanes with c == q*4+r (replicated over q)
        float x2row = __shfl(part, q * 4 + r, 64);
        float rowf = fast_exp2(fmaf(-LOG2E, x2row, BIASF));
        psum[rt][r] = fmaf(v, rowf, bval);
      }
      if (c == 0) {
        f32x4 o = {psum[rt][0], psum[rt][1], psum[rt][2], psum[rt][3]};
        *reinterpret_cast<f32x4*>(out + rowbase + rt * 16 + q * 4) = o;
      }
    }
  }
}

extern "C" void kernel_launch(void* const* d_in, const int* in_sizes, int n_in,
                              void* d_out, int out_size, void* d_ws, size_t ws_size,
                              hipStream_t stream) {
  const float* X       = (const float*)d_in[0];
  const float* centers = (const float*)d_in[1];
  const float* w       = (const float*)d_in[2];
  const float* b       = (const float*)d_in[3];
  float* out = (float*)d_out;

  rbf_main<<<GRID, 512, 0, stream>>>(X, b, centers, w, out);
}